// Round 1
// baseline (456.222 us; speedup 1.0000x reference)
//
#include <hip/hip_runtime.h>
#include <hip/hip_bf16.h>
#include <cstdint>
#include <cstddef>

typedef unsigned short u16;
typedef __bf16 bf16x8 __attribute__((ext_vector_type(8)));
typedef float    f32x4 __attribute__((ext_vector_type(4)));
typedef unsigned short u16x2 __attribute__((ext_vector_type(2)));
typedef unsigned short u16x4 __attribute__((ext_vector_type(4)));
typedef unsigned short u16x8 __attribute__((ext_vector_type(8)));

#define DEVI static __device__ __forceinline__

DEVI float b2f(u16 u){ union{unsigned i; float v;} x; x.i=((unsigned)u)<<16; return x.v; }
DEVI u16 f2b(float f){ union{float v; unsigned i;} x; x.v=f; unsigned r=x.i+0x7FFFu+((x.i>>16)&1u); return (u16)(r>>16); }
DEVI f32x4 mfma16(bf16x8 a, bf16x8 b, f32x4 c){ return __builtin_amdgcn_mfma_f32_16x16x32_bf16(a,b,c,0,0,0); }
DEVI void gload16(const void* g, void* l){
  __builtin_amdgcn_global_load_lds((const __attribute__((address_space(1))) void*)g,
                                   (__attribute__((address_space(3))) void*)l, 16, 0, 0);
}
DEVI float silu_f(float x){ return x/(1.f+__expf(-x)); }

// ---------------- workspace layout (bytes) ----------------
static constexpr size_t OFF_WC   = 0;
static constexpr size_t OFF_WQKV = OFF_WC   + (size_t)1024*1024*2;
static constexpr size_t OFF_WPROJ= OFF_WQKV + (size_t)3072*1024*2;
static constexpr size_t OFF_WEXP = OFF_WPROJ+ (size_t)1024*1024*2;
static constexpr size_t OFF_WW12 = OFF_WEXP + (size_t)1024*1024*2;
static constexpr size_t OFF_WW3  = OFF_WW12 + (size_t)5504*1024*2;
static constexpr size_t OFF_ADA  = OFF_WW3  + (size_t)1024*2752*2;
static constexpr size_t OFF_X2   = OFF_ADA  + (size_t)4*6144*4;
static constexpr size_t OFF_P1   = OFF_X2   + (size_t)4096*1024*4;
static constexpr size_t OFF_H1   = OFF_P1;
static constexpr size_t OFF_HC   = OFF_H1   + (size_t)4096*1024*2;
static constexpr size_t OFF_QKVO = OFF_HC   + (size_t)4096*1024*2;
static constexpr size_t OFF_X12  = OFF_P1;                       // reuse: h1/hc/qkvO dead
static constexpr size_t OFF_P2   = OFF_P1   + (size_t)4096*5504*2;
static constexpr size_t OFF_Q    = OFF_P2;
static constexpr size_t OFF_K    = OFF_Q    + (size_t)64*1024*64*2;
static constexpr size_t OFF_VT   = OFF_K    + (size_t)64*1024*64*2;
static constexpr size_t OFF_O    = OFF_VT   + (size_t)64*1024*64*2;
static constexpr size_t OFF_PR   = OFF_O    + (size_t)4096*1024*2;
static constexpr size_t OFF_H2   = OFF_PR   + (size_t)4096*1024*2;
static constexpr size_t OFF_HID  = OFF_P2;                       // reuse: q/k/vt dead

// ---------------- fp32 -> bf16 weight conversion with zero padding ----------------
__global__ __launch_bounds__(256) void convert_pad(const float* __restrict__ src, u16* __restrict__ dst,
                                                   int R, int C, int Cpad)
{
  int r = blockIdx.y;
  int c0 = (blockIdx.x*256 + threadIdx.x)*4;
  if (c0 >= Cpad) return;
  u16x4 o;
#pragma unroll
  for (int j=0;j<4;j++){
    int cc = c0+j;
    float f = (r < R && cc < C) ? src[(size_t)r*C + cc] : 0.f;
    o[j] = f2b(f);
  }
  *(u16x4*)&dst[(size_t)r*Cpad + c0] = o;
}

// ---------------- adaLN: ada = silu(c) @ ada_w.T + ada_b  -> [4][6144] fp32 ----------------
__global__ __launch_bounds__(256) void ada_kernel(const float* __restrict__ c,
    const float* __restrict__ aw, const float* __restrict__ ab, float* __restrict__ ada)
{
  __shared__ float s[4][1024];
  int t = threadIdx.x;
#pragma unroll
  for (int i=0;i<16;i++){
    int idx = i*256 + t;
    float cv = c[idx];
    s[idx>>10][idx&1023] = cv/(1.f+__expf(-cv));
  }
  __syncthreads();
  int wid = t>>6, lane = t&63;
  int j = blockIdx.x*4 + wid;
  const f32x4* wp = (const f32x4*)(aw + (size_t)j*1024);
  float a0=0,a1=0,a2=0,a3=0;
#pragma unroll
  for (int i=0;i<4;i++){
    f32x4 wv = wp[i*64 + lane];
    int k0 = (i*64+lane)*4;
#pragma unroll
    for (int e=0;e<4;e++){
      float w = wv[e];
      a0 += w*s[0][k0+e]; a1 += w*s[1][k0+e]; a2 += w*s[2][k0+e]; a3 += w*s[3][k0+e];
    }
  }
#pragma unroll
  for (int mask=1; mask<64; mask<<=1){
    a0 += __shfl_xor(a0, mask); a1 += __shfl_xor(a1, mask);
    a2 += __shfl_xor(a2, mask); a3 += __shfl_xor(a3, mask);
  }
  if (lane==0){
    float bv = ab[j];
    ada[0*6144 + j] = a0 + bv;
    ada[1*6144 + j] = a1 + bv;
    ada[2*6144 + j] = a2 + bv;
    ada[3*6144 + j] = a3 + bv;
  }
}

// ---------------- fused RMSNorm + modulate -> bf16 ----------------
__global__ __launch_bounds__(256) void rms_mod(const float* __restrict__ x,
    const float* __restrict__ w, const float* __restrict__ ada, int chunkSh,
    u16* __restrict__ out)
{
  int row = blockIdx.x;
  int b = row>>10;
  int t = threadIdx.x;
  int wid = t>>6, lane = t&63;
  f32x4 v = *(const f32x4*)(x + (size_t)row*1024 + t*4);
  float ss = v[0]*v[0]+v[1]*v[1]+v[2]*v[2]+v[3]*v[3];
#pragma unroll
  for (int mask=1; mask<64; mask<<=1) ss += __shfl_xor(ss, mask);
  __shared__ float red[4];
  if (lane==0) red[wid]=ss;
  __syncthreads();
  float rinv = rsqrtf((red[0]+red[1]+red[2]+red[3])*(1.f/1024.f) + 1e-6f);
  int cc = t*4;
  const float* shp = ada + (size_t)b*6144 + (size_t)chunkSh*1024 + cc;
  u16x4 o;
#pragma unroll
  for (int jj=0;jj<4;jj++){
    float val = v[jj]*rinv*w[cc+jj];
    val = val*(1.f+shp[jj+1024]) + shp[jj];
    o[jj] = f2b(val);
  }
  *(u16x4*)&out[(size_t)row*1024 + cc] = o;
}

// ---------------- bf16 GEMM: C = A[M,K] * Bw[N,K]^T (+bias) ----------------
// EPI 0: store bf16 at outb, ld = N (padded). EPI 1: outf = xres + gate*(acc+bias), ld=1024.
template<int EPI>
__global__ __launch_bounds__(256,2) void gemm_bt(
    const u16* __restrict__ A, const u16* __restrict__ Bw, const float* __restrict__ bias,
    int N, int K, int nbias, u16* __restrict__ outb,
    const float* __restrict__ xres, const float* __restrict__ ada, int adaChunk,
    float* __restrict__ outf)
{
  __shared__ __align__(16) u16 As[128*32];
  __shared__ __align__(16) u16 Bs[128*32];
  int t = threadIdx.x;
  int wid = t>>6, lane = t&63;
  int lr = lane&15, lg = lane>>4;
  int bm = blockIdx.y, bn = blockIdx.x;
  const u16* pA = A  + (size_t)(bm*128 + (t>>2))*K + (t&3)*8;
  const u16* pB = Bw + (size_t)(bn*128 + (t>>2))*K + (t&3)*8;
  u16* lA = As + t*8;
  u16* lB = Bs + t*8;
  int wr = (wid>>1)*64, wc = (wid&1)*64;
  f32x4 acc[4][4] = {};
  for (int kk=0; kk<K; kk+=32){
    gload16(pA, lA);
    gload16(pA + (size_t)64*K, lA + 64*32);
    gload16(pB, lB);
    gload16(pB + (size_t)64*K, lB + 64*32);
    pA += 32; pB += 32;
    __syncthreads();
    bf16x8 af[4], bfr[4];
#pragma unroll
    for (int m=0;m<4;m++) af[m]  = *(const bf16x8*)&As[(wr + m*16 + lr)*32 + lg*8];
#pragma unroll
    for (int n=0;n<4;n++) bfr[n] = *(const bf16x8*)&Bs[(wc + n*16 + lr)*32 + lg*8];
#pragma unroll
    for (int m=0;m<4;m++)
#pragma unroll
      for (int n=0;n<4;n++)
        acc[m][n] = mfma16(af[m], bfr[n], acc[m][n]);
    __syncthreads();
  }
#pragma unroll
  for (int n=0;n<4;n++){
    int col = bn*128 + wc + n*16 + lr;
    float bv = (col < nbias) ? bias[col] : 0.f;
#pragma unroll
    for (int m=0;m<4;m++){
      int row0 = bm*128 + wr + m*16 + lg*4;
#pragma unroll
      for (int r=0;r<4;r++){
        int row = row0 + r;
        float v = acc[m][n][r] + bv;
        if constexpr (EPI==0){
          outb[(size_t)row*N + col] = f2b(v);
        } else {
          int bb = row>>10;
          float g = ada[(size_t)bb*6144 + (size_t)adaChunk*1024 + col];
          outf[(size_t)row*1024 + col] = xres[(size_t)row*1024 + col] + g*v;
        }
      }
    }
  }
}

// ---------------- qkv repack: rms-norm q,k per head (q pre-scaled by 1/8), v transposed ----------------
__global__ __launch_bounds__(256) void repack_qkv(const u16* __restrict__ qkvO,
    const float* __restrict__ qnw, const float* __restrict__ knw,
    u16* __restrict__ qO, u16* __restrict__ kO, u16* __restrict__ vtO)
{
  __shared__ u16 ldsv[64][64];
  int bh = blockIdx.y, b = bh>>4, h = bh&15;
  int n0 = blockIdx.x*64;
  int t = threadIdx.x;
  int nr = t>>2, qd = (t&3)*16;
  const u16* rowp = qkvO + (size_t)(b*1024 + n0 + nr)*3072;
  // Q: rms-norm * qn_w * (1/8)
  {
    u16x8 a0 = *(const u16x8*)(rowp + h*64 + qd);
    u16x8 a1 = *(const u16x8*)(rowp + h*64 + qd + 8);
    float f[16]; float ss=0;
#pragma unroll
    for (int jj=0;jj<8;jj++){ f[jj]=b2f(a0[jj]); f[8+jj]=b2f(a1[jj]); }
#pragma unroll
    for (int jj=0;jj<16;jj++) ss += f[jj]*f[jj];
    ss += __shfl_xor(ss,1); ss += __shfl_xor(ss,2);
    float rinv = rsqrtf(ss*(1.f/64.f)+1e-6f)*0.125f;
    u16x8 o0,o1;
#pragma unroll
    for (int jj=0;jj<8;jj++){ o0[jj]=f2b(f[jj]*rinv*qnw[qd+jj]); o1[jj]=f2b(f[8+jj]*rinv*qnw[qd+8+jj]); }
    u16* dst = qO + ((size_t)bh*1024 + n0 + nr)*64 + qd;
    *(u16x8*)dst = o0; *(u16x8*)(dst+8) = o1;
  }
  // K: rms-norm * kn_w
  {
    u16x8 a0 = *(const u16x8*)(rowp + 1024 + h*64 + qd);
    u16x8 a1 = *(const u16x8*)(rowp + 1024 + h*64 + qd + 8);
    float f[16]; float ss=0;
#pragma unroll
    for (int jj=0;jj<8;jj++){ f[jj]=b2f(a0[jj]); f[8+jj]=b2f(a1[jj]); }
#pragma unroll
    for (int jj=0;jj<16;jj++) ss += f[jj]*f[jj];
    ss += __shfl_xor(ss,1); ss += __shfl_xor(ss,2);
    float rinv = rsqrtf(ss*(1.f/64.f)+1e-6f);
    u16x8 o0,o1;
#pragma unroll
    for (int jj=0;jj<8;jj++){ o0[jj]=f2b(f[jj]*rinv*knw[qd+jj]); o1[jj]=f2b(f[8+jj]*rinv*knw[qd+8+jj]); }
    u16* dst = kO + ((size_t)bh*1024 + n0 + nr)*64 + qd;
    *(u16x8*)dst = o0; *(u16x8*)(dst+8) = o1;
  }
  // V: transpose to [bh][d][n]
  {
    u16x8 a0 = *(const u16x8*)(rowp + 2048 + h*64 + qd);
    u16x8 a1 = *(const u16x8*)(rowp + 2048 + h*64 + qd + 8);
#pragma unroll
    for (int jj=0;jj<8;jj++){ ldsv[qd+jj][nr] = a0[jj]; ldsv[qd+8+jj][nr] = a1[jj]; }
  }
  __syncthreads();
  {
    int d = t>>2, ns = (t&3)*16;
    u16x8 r0 = *(const u16x8*)&ldsv[d][ns];
    u16x8 r1 = *(const u16x8*)&ldsv[d][ns+8];
    u16* dst = vtO + ((size_t)bh*64 + d)*1024 + n0 + ns;
    *(u16x8*)dst = r0; *(u16x8*)(dst+8) = r1;
  }
}

// ---------------- flash attention (swapped QK^T, online softmax) ----------------
// grid (16 qblocks, 64 bh); 4 waves, 16 q-rows each. Softmax scale folded into q.
__global__ __launch_bounds__(256,2) void attn_fwd(const u16* __restrict__ qO,
    const u16* __restrict__ kO, const u16* __restrict__ vtO, u16* __restrict__ o)
{
  __shared__ __align__(16) u16 plds[4][16][32];
  int bh = blockIdx.y, b = bh>>4, h = bh&15;
  int wid = threadIdx.x>>6, lane = threadIdx.x&63;
  int lr = lane&15, lg = lane>>4;
  int q0 = blockIdx.x*64 + wid*16;
  const u16* qp = qO + ((size_t)bh*1024 + q0 + lr)*64 + lg*8;
  bf16x8 qf0 = *(const bf16x8*)qp;
  bf16x8 qf1 = *(const bf16x8*)(qp + 32);
  const u16* kb = kO  + (size_t)bh*1024*64;
  const u16* vb = vtO + (size_t)bh*64*1024;
  f32x4 oacc[4] = {};
  float mrun = -1e30f, lrun = 0.f;
#pragma unroll 2
  for (int kk=0; kk<1024; kk+=32){
    const u16* kp = kb + (size_t)(kk + lr)*64 + lg*8;
    bf16x8 k00 = *(const bf16x8*)kp;
    bf16x8 k01 = *(const bf16x8*)(kp + 32);
    bf16x8 k10 = *(const bf16x8*)(kp + 16*64);
    bf16x8 k11 = *(const bf16x8*)(kp + 16*64 + 32);
    f32x4 s0 = {}, s1 = {};
    s0 = mfma16(k00, qf0, s0); s0 = mfma16(k01, qf1, s0);
    s1 = mfma16(k10, qf0, s1); s1 = mfma16(k11, qf1, s1);
    // S^T layout: lane holds q=lr, kv = kk + {0,16} + lg*4 + r
    float pm = s0[0];
#pragma unroll
    for (int r=1;r<4;r++) pm = fmaxf(pm, s0[r]);
#pragma unroll
    for (int r=0;r<4;r++) pm = fmaxf(pm, s1[r]);
    pm = fmaxf(pm, __shfl_xor(pm, 16));
    pm = fmaxf(pm, __shfl_xor(pm, 32));
    float mnew = fmaxf(mrun, pm);
    float alpha = __expf(mrun - mnew);
    float p0[4], p1[4]; float ls = 0.f;
#pragma unroll
    for (int r=0;r<4;r++){ p0[r]=__expf(s0[r]-mnew); p1[r]=__expf(s1[r]-mnew); ls += p0[r]+p1[r]; }
    ls += __shfl_xor(ls, 16); ls += __shfl_xor(ls, 32);
    lrun = lrun*alpha + ls; mrun = mnew;
    u16x4 w0, w1;
#pragma unroll
    for (int r=0;r<4;r++){ w0[r]=f2b(p0[r]); w1[r]=f2b(p1[r]); }
    *(u16x4*)&plds[wid][lr][lg*4] = w0;
    *(u16x4*)&plds[wid][lr][16 + lg*4] = w1;
    asm volatile("" ::: "memory");
    bf16x8 pa = *(const bf16x8*)&plds[wid][lr][lg*8];
    float ar[4];
#pragma unroll
    for (int r=0;r<4;r++) ar[r] = __shfl(alpha, lg*4 + r);
#pragma unroll
    for (int tt=0;tt<4;tt++){
      bf16x8 vv = *(const bf16x8*)(vb + (size_t)(tt*16 + lr)*1024 + kk + lg*8);
#pragma unroll
      for (int r=0;r<4;r++) oacc[tt][r] *= ar[r];
      oacc[tt] = mfma16(pa, vv, oacc[tt]);
    }
  }
  float li = 1.f/lrun;
  float linv[4];
#pragma unroll
  for (int r=0;r<4;r++) linv[r] = __shfl(li, lg*4 + r);
#pragma unroll
  for (int tt=0;tt<4;tt++){
#pragma unroll
    for (int r=0;r<4;r++){
      int row = (b<<10) + blockIdx.x*64 + wid*16 + lg*4 + r;
      int col = h*64 + tt*16 + lr;
      o[(size_t)row*1024 + col] = f2b(oacc[tt][r]*linv[r]);
    }
  }
}

// ---------------- SwiGLU: hid = silu(x1)*x2, zero-padded to 2752 cols ----------------
__global__ __launch_bounds__(256) void swiglu_k(const u16* __restrict__ x12, u16* __restrict__ hid)
{
  int r = blockIdx.y;
  int c4 = blockIdx.x*256 + threadIdx.x;
  if (c4 >= 688) return;
  int cc = c4*4;
  const u16* rowp = x12 + (size_t)r*5504;
  u16x4 x1 = *(const u16x4*)(rowp + cc);
  u16x2 x2a = *(const u16x2*)(rowp + 2730 + cc);
  u16x2 x2b = *(const u16x2*)(rowp + 2730 + cc + 2);
  u16 x2v[4] = {x2a[0],x2a[1],x2b[0],x2b[1]};
  u16x4 o;
#pragma unroll
  for (int jj=0;jj<4;jj++){
    float a = b2f(x1[jj]);
    float g = silu_f(a)*b2f(x2v[jj]);
    o[jj] = (cc+jj < 2730) ? f2b(g) : (u16)0;
  }
  *(u16x4*)&hid[(size_t)r*2752 + cc] = o;
}

extern "C" void kernel_launch(void* const* d_in, const int* in_sizes, int n_in,
                              void* d_out, int out_size, void* d_ws, size_t ws_size,
                              hipStream_t stream)
{
  (void)in_sizes; (void)n_in; (void)out_size; (void)ws_size;
  const float* x    = (const float*)d_in[0];
  const float* c    = (const float*)d_in[1];
  const float* n1w  = (const float*)d_in[2];
  const float* cw   = (const float*)d_in[3];
  const float* cb   = (const float*)d_in[4];
  const float* qkvw = (const float*)d_in[5];
  const float* qkvb = (const float*)d_in[6];
  const float* qnw  = (const float*)d_in[7];
  const float* knw  = (const float*)d_in[8];
  const float* pw   = (const float*)d_in[9];
  const float* pb   = (const float*)d_in[10];
  const float* ew   = (const float*)d_in[11];
  const float* eb   = (const float*)d_in[12];
  const float* n2w  = (const float*)d_in[13];
  const float* w12w = (const float*)d_in[14];
  const float* w12b = (const float*)d_in[15];
  const float* w3w  = (const float*)d_in[16];
  const float* w3b  = (const float*)d_in[17];
  const float* adaw = (const float*)d_in[18];
  const float* adab = (const float*)d_in[19];
  float* out = (float*)d_out;
  char* ws = (char*)d_ws;
  auto U = [&](size_t off){ return (u16*)(ws + off); };
  auto F = [&](size_t off){ return (float*)(ws + off); };

  // weight conversions (bf16, zero-padded)
  convert_pad<<<dim3(1,1024), 256, 0, stream>>>(cw,   U(OFF_WC),   1024, 1024, 1024);
  convert_pad<<<dim3(1,3072), 256, 0, stream>>>(qkvw, U(OFF_WQKV), 3072, 1024, 1024);
  convert_pad<<<dim3(1,1024), 256, 0, stream>>>(pw,   U(OFF_WPROJ),1024, 1024, 1024);
  convert_pad<<<dim3(1,1024), 256, 0, stream>>>(ew,   U(OFF_WEXP), 1024, 1024, 1024);
  convert_pad<<<dim3(1,5504), 256, 0, stream>>>(w12w, U(OFF_WW12), 5460, 1024, 1024);
  convert_pad<<<dim3(3,1024), 256, 0, stream>>>(w3w,  U(OFF_WW3),  1024, 2730, 2752);

  ada_kernel<<<1536, 256, 0, stream>>>(c, adaw, adab, F(OFF_ADA));

  // attention branch
  rms_mod<<<4096, 256, 0, stream>>>(x, n1w, F(OFF_ADA), 0, U(OFF_H1));
  gemm_bt<0><<<dim3(8,32),  256, 0, stream>>>(U(OFF_H1), U(OFF_WC),   cb,   1024, 1024, 1024, U(OFF_HC),   nullptr, nullptr, 0, nullptr);
  gemm_bt<0><<<dim3(24,32), 256, 0, stream>>>(U(OFF_HC), U(OFF_WQKV), qkvb, 3072, 1024, 3072, U(OFF_QKVO), nullptr, nullptr, 0, nullptr);
  repack_qkv<<<dim3(16,64), 256, 0, stream>>>(U(OFF_QKVO), qnw, knw, U(OFF_Q), U(OFF_K), U(OFF_VT));
  attn_fwd<<<dim3(16,64), 256, 0, stream>>>(U(OFF_Q), U(OFF_K), U(OFF_VT), U(OFF_O));
  gemm_bt<0><<<dim3(8,32), 256, 0, stream>>>(U(OFF_O),  U(OFF_WPROJ), pb, 1024, 1024, 1024, U(OFF_PR), nullptr, nullptr, 0, nullptr);
  gemm_bt<1><<<dim3(8,32), 256, 0, stream>>>(U(OFF_PR), U(OFF_WEXP),  eb, 1024, 1024, 1024, nullptr, x, F(OFF_ADA), 2, F(OFF_X2));

  // FFN branch
  rms_mod<<<4096, 256, 0, stream>>>(F(OFF_X2), n2w, F(OFF_ADA), 3, U(OFF_H2));
  gemm_bt<0><<<dim3(43,32), 256, 0, stream>>>(U(OFF_H2), U(OFF_WW12), w12b, 5504, 1024, 5460, U(OFF_X12), nullptr, nullptr, 0, nullptr);
  swiglu_k<<<dim3(3,4096), 256, 0, stream>>>(U(OFF_X12), U(OFF_HID));
  gemm_bt<1><<<dim3(8,32), 256, 0, stream>>>(U(OFF_HID), U(OFF_WW3), w3b, 1024, 2752, 1024, nullptr, F(OFF_X2), F(OFF_ADA), 5, out);
}